// Round 1
// baseline (59.885 us; speedup 1.0000x reference)
//
#include <hip/hip_runtime.h>
#include <math.h>

#define NPARTS 8
#define NKP 32768
#define BDIM 64
#define NJ 7

// d_out flat layout (return-order concatenation)
#define OFF_OBJ    0
#define OFF_BASET  1
#define OFF_REL    17
#define OFF_NANCH  129
#define OFF_NAXIS  150
#define OFF_JLOC   171
#define OFF_JAXIS  192
#define OFF_NKPOUT 213
// total = 213 + 786432 = 786645

// ---------------------------------------------------------------------------
// Kernel A: all the tiny pose math. 1 block, 64 threads.
//  - every thread recomputes R/base_T (cheap, avoids sync)
//  - thread j<7 handles joint j; thread 7 handles base outputs + reg init
//  - writes the 8 per-part 4x4 transforms into d_ws (allT)
// ---------------------------------------------------------------------------
__global__ void setup_kernel(const float* __restrict__ quat,
                             const float* __restrict__ base_t,
                             const float* __restrict__ jstate,
                             const float* __restrict__ beta,
                             const float* __restrict__ W_loc,
                             const float* __restrict__ W_axis,
                             float* __restrict__ out,
                             float* __restrict__ allT) {
  int t = threadIdx.x;
  float q0 = quat[0], q1 = quat[1], q2 = quat[2], q3 = quat[3];
  float qn = sqrtf(q0 * q0 + q1 * q1 + q2 * q2 + q3 * q3);
  float a = q0 / qn, b = q1 / qn, c = q2 / qn, d = q3 / qn;
  float R00 = 1.f - 2.f * c * c - 2.f * d * d, R01 = 2.f * b * c - 2.f * a * d,
        R02 = 2.f * a * c + 2.f * b * d;
  float R10 = 2.f * b * c + 2.f * a * d, R11 = 1.f - 2.f * b * b - 2.f * d * d,
        R12 = 2.f * c * d - 2.f * a * b;
  float R20 = 2.f * b * d - 2.f * a * c, R21 = 2.f * a * b + 2.f * c * d,
        R22 = 1.f - 2.f * b * b - 2.f * c * c;
  float t0 = base_t[0], t1 = base_t[1], t2 = base_t[2];
  float T[16] = {R00, R01, R02, t0, R10, R11, R12, t1,
                 R20, R21, R22, t2, 0.f, 0.f, 0.f, 1.f};

  if (t == 7) {
    for (int i = 0; i < 16; i++) {
      out[OFF_BASET + i] = T[i];
      allT[i] = T[i];
    }
    float s = 0.f;
    for (int e = 0; e < BDIM; e++) {
      float be = beta[e];
      s += be * be;
    }
    out[OFF_OBJ] = (s / (float)BDIM) * 0.001f;  // reg term; obj_kernel atomicAdds onto this
  }

  if (t < NJ) {
    int j = t;
    float l0 = 0.f, l1 = 0.f, l2 = 0.f, x0 = 0.f, x1 = 0.f, x2 = 0.f;
    for (int e = 0; e < BDIM; e++) {
      float be = beta[e];
      l0 += be * W_loc[e * 21 + j * 3 + 0];
      l1 += be * W_loc[e * 21 + j * 3 + 1];
      l2 += be * W_loc[e * 21 + j * 3 + 2];
      x0 += be * W_axis[e * 21 + j * 3 + 0];
      x1 += be * W_axis[e * 21 + j * 3 + 1];
      x2 += be * W_axis[e * 21 + j * 3 + 2];
    }
    float xn = sqrtf(x0 * x0 + x1 * x1 + x2 * x2);
    x0 /= xn; x1 /= xn; x2 /= xn;
    out[OFF_JLOC + j * 3 + 0] = l0;
    out[OFF_JLOC + j * 3 + 1] = l1;
    out[OFF_JLOC + j * 3 + 2] = l2;
    out[OFF_JAXIS + j * 3 + 0] = x0;
    out[OFF_JAXIS + j * 3 + 1] = x1;
    out[OFF_JAXIS + j * 3 + 2] = x2;

    // new_anchor = R*loc + t ; new_axis = R*axis
    float aa = R00 * l0 + R01 * l1 + R02 * l2 + t0;
    float bb = R10 * l0 + R11 * l1 + R12 * l2 + t1;
    float cc = R20 * l0 + R21 * l1 + R22 * l2 + t2;
    float u = R00 * x0 + R01 * x1 + R02 * x2;
    float v = R10 * x0 + R11 * x1 + R12 * x2;
    float w = R20 * x0 + R21 * x1 + R22 * x2;
    out[OFF_NANCH + j * 3 + 0] = aa;
    out[OFF_NANCH + j * 3 + 1] = bb;
    out[OFF_NANCH + j * 3 + 2] = cc;
    out[OFF_NAXIS + j * 3 + 0] = u;
    out[OFF_NAXIS + j * 3 + 1] = v;
    out[OFF_NAXIS + j * 3 + 2] = w;

    float th = jstate[j];
    float cth = cosf(-th), sth = sinf(-th), omc = 1.f - cth;
    float rel[16];
    rel[0] = u * u + (v * v + w * w) * cth;
    rel[1] = u * v * omc - w * sth;
    rel[2] = u * w * omc + v * sth;
    rel[3] = (aa * (v * v + w * w) - u * (bb * v + cc * w)) * omc + (bb * w - cc * v) * sth;
    rel[4] = u * v * omc + w * sth;
    rel[5] = v * v + (u * u + w * w) * cth;
    rel[6] = v * w * omc - u * sth;
    rel[7] = (bb * (u * u + w * w) - v * (aa * u + cc * w)) * omc + (cc * u - aa * w) * sth;
    rel[8] = u * w * omc - v * sth;
    rel[9] = v * w * omc + u * sth;
    rel[10] = w * w + (u * u + v * v) * cth;
    rel[11] = (cc * (u * u + v * v) - w * (aa * u + bb * v)) * omc + (aa * v - bb * u) * sth;
    rel[12] = 0.f; rel[13] = 0.f; rel[14] = 0.f; rel[15] = 1.f;
    for (int i = 0; i < 16; i++) out[OFF_REL + j * 16 + i] = rel[i];

    // child_T = rel @ base_T
    for (int r = 0; r < 4; r++)
      for (int cix = 0; cix < 4; cix++) {
        float s = 0.f;
        for (int k2 = 0; k2 < 4; k2++) s += rel[r * 4 + k2] * T[k2 * 4 + cix];
        allT[(j + 1) * 16 + r * 4 + cix] = s;
      }
  }
}

// ---------------------------------------------------------------------------
// Kernel B: norm_kp = einsum('e,e{pkd}->pkd', beta, W_kp). Memory-bound pass
// over 201 MB. One float4 per thread; 64 strided (3 MB apart) coalesced loads.
// Output region is only 4B-aligned (float offset 213) -> scalar stores.
// ---------------------------------------------------------------------------
__global__ __launch_bounds__(256) void einsum_kernel(
    const float* __restrict__ W_kp, const float* __restrict__ beta,
    float* __restrict__ out_nkp) {
  __shared__ float sb[BDIM];
  int tid = threadIdx.x;
  if (tid < BDIM) sb[tid] = beta[tid];
  __syncthreads();
  int i = blockIdx.x * blockDim.x + tid;  // float4 index, 196608 total
  const float4* __restrict__ W4 = (const float4*)W_kp;
  float ax = 0.f, ay = 0.f, az = 0.f, aw = 0.f;
#pragma unroll 16
  for (int e = 0; e < BDIM; e++) {
    float be = sb[e];
    float4 vv = W4[e * (NPARTS * NKP * 3 / 4) + i];
    ax += be * vv.x;
    ay += be * vv.y;
    az += be * vv.z;
    aw += be * vv.w;
  }
  float* o = out_nkp + i * 4;
  o[0] = ax; o[1] = ay; o[2] = az; o[3] = aw;
}

// ---------------------------------------------------------------------------
// Kernel C: weighted distance objective. One point per thread; per-part 4x4
// transform via LDS; wave shfl + LDS block reduce; one atomicAdd per block.
// 4th homogeneous component cancels (both sides == 1), so 3-component norm.
// ---------------------------------------------------------------------------
__global__ __launch_bounds__(256) void obj_kernel(
    const float* __restrict__ nkp, const float* __restrict__ pred_kp,
    const float* __restrict__ wgt, const float* __restrict__ allT,
    float* __restrict__ out_obj) {
  __shared__ float Ts[16];
  __shared__ float red[4];
  int tid = threadIdx.x;
  int gid = blockIdx.x * 256 + tid;  // 0..262143
  int p = gid >> 15;                 // uniform per block (128 blocks/part)
  if (tid < 16) Ts[tid] = allT[p * 16 + tid];
  __syncthreads();
  int o3 = gid * 3;
  float x = nkp[o3], y = nkp[o3 + 1], z = nkp[o3 + 2];
  float px = pred_kp[o3], py = pred_kp[o3 + 1], pz = pred_kp[o3 + 2];
  float w = wgt[gid];
  float dx = Ts[0] * x + Ts[1] * y + Ts[2] * z + Ts[3] - px;
  float dy = Ts[4] * x + Ts[5] * y + Ts[6] * z + Ts[7] - py;
  float dz = Ts[8] * x + Ts[9] * y + Ts[10] * z + Ts[11] - pz;
  float v = sqrtf(dx * dx + dy * dy + dz * dz) * w;
#pragma unroll
  for (int off = 32; off > 0; off >>= 1) v += __shfl_down(v, off, 64);
  if ((tid & 63) == 0) red[tid >> 6] = v;
  __syncthreads();
  if (tid == 0) {
    float s = (red[0] + red[1] + red[2] + red[3]) * (1.0f / (float)(NPARTS * NKP));
    atomicAdd(out_obj, s);
  }
}

extern "C" void kernel_launch(void* const* d_in, const int* in_sizes, int n_in,
                              void* d_out, int out_size, void* d_ws, size_t ws_size,
                              hipStream_t stream) {
  const float* pred_kp = (const float*)d_in[0];
  const float* quat    = (const float*)d_in[1];
  const float* base_t  = (const float*)d_in[2];
  const float* jstate  = (const float*)d_in[3];
  const float* beta    = (const float*)d_in[4];
  const float* wgt     = (const float*)d_in[5];
  const float* W_kp    = (const float*)d_in[6];
  const float* W_loc   = (const float*)d_in[7];
  const float* W_axis  = (const float*)d_in[8];
  float* out  = (float*)d_out;
  float* allT = (float*)d_ws;  // 8 * 16 floats

  setup_kernel<<<1, 64, 0, stream>>>(quat, base_t, jstate, beta, W_loc, W_axis, out, allT);
  einsum_kernel<<<(NPARTS * NKP * 3 / 4) / 256, 256, 0, stream>>>(W_kp, beta, out + OFF_NKPOUT);
  obj_kernel<<<(NPARTS * NKP) / 256, 256, 0, stream>>>(out + OFF_NKPOUT, pred_kp, wgt, allT, out);
}

// Round 2
// 58.601 us; speedup vs baseline: 1.0219x; 1.0219x over previous
//
#include <hip/hip_runtime.h>
#include <math.h>

#define NPARTS 8
#define NKP 32768
#define BDIM 64
#define NJ 7
#define NPTS (NPARTS * NKP)        // 262144 points
#define WSTRIDE (NPTS * 3)         // 786432 floats per beta slice

// d_out flat layout (return-order concatenation)
#define OFF_OBJ    0
#define OFF_BASET  1
#define OFF_REL    17
#define OFF_NANCH  129
#define OFF_NAXIS  150
#define OFF_JLOC   171
#define OFF_JAXIS  192
#define OFF_NKPOUT 213
// total = 213 + 786432 = 786645

// ---------------------------------------------------------------------------
// Kernel A: tiny pose math. 1 block, 64 threads. Writes small outputs,
// the 8 per-part 4x4 transforms into d_ws, and out[0] = beta regularizer
// (fused kernel atomicAdds the data term onto it -> fresh value every call).
// ---------------------------------------------------------------------------
__global__ void setup_kernel(const float* __restrict__ quat,
                             const float* __restrict__ base_t,
                             const float* __restrict__ jstate,
                             const float* __restrict__ beta,
                             const float* __restrict__ W_loc,
                             const float* __restrict__ W_axis,
                             float* __restrict__ out,
                             float* __restrict__ allT) {
  int t = threadIdx.x;
  float q0 = quat[0], q1 = quat[1], q2 = quat[2], q3 = quat[3];
  float qn = sqrtf(q0 * q0 + q1 * q1 + q2 * q2 + q3 * q3);
  float a = q0 / qn, b = q1 / qn, c = q2 / qn, d = q3 / qn;
  float R00 = 1.f - 2.f * c * c - 2.f * d * d, R01 = 2.f * b * c - 2.f * a * d,
        R02 = 2.f * a * c + 2.f * b * d;
  float R10 = 2.f * b * c + 2.f * a * d, R11 = 1.f - 2.f * b * b - 2.f * d * d,
        R12 = 2.f * c * d - 2.f * a * b;
  float R20 = 2.f * b * d - 2.f * a * c, R21 = 2.f * a * b + 2.f * c * d,
        R22 = 1.f - 2.f * b * b - 2.f * c * c;
  float t0 = base_t[0], t1 = base_t[1], t2 = base_t[2];
  float T[16] = {R00, R01, R02, t0, R10, R11, R12, t1,
                 R20, R21, R22, t2, 0.f, 0.f, 0.f, 1.f};

  if (t == 7) {
    for (int i = 0; i < 16; i++) {
      out[OFF_BASET + i] = T[i];
      allT[i] = T[i];
    }
    float s = 0.f;
    for (int e = 0; e < BDIM; e++) {
      float be = beta[e];
      s += be * be;
    }
    out[OFF_OBJ] = (s / (float)BDIM) * 0.001f;
  }

  if (t < NJ) {
    int j = t;
    float l0 = 0.f, l1 = 0.f, l2 = 0.f, x0 = 0.f, x1 = 0.f, x2 = 0.f;
    for (int e = 0; e < BDIM; e++) {
      float be = beta[e];
      l0 += be * W_loc[e * 21 + j * 3 + 0];
      l1 += be * W_loc[e * 21 + j * 3 + 1];
      l2 += be * W_loc[e * 21 + j * 3 + 2];
      x0 += be * W_axis[e * 21 + j * 3 + 0];
      x1 += be * W_axis[e * 21 + j * 3 + 1];
      x2 += be * W_axis[e * 21 + j * 3 + 2];
    }
    float xn = sqrtf(x0 * x0 + x1 * x1 + x2 * x2);
    x0 /= xn; x1 /= xn; x2 /= xn;
    out[OFF_JLOC + j * 3 + 0] = l0;
    out[OFF_JLOC + j * 3 + 1] = l1;
    out[OFF_JLOC + j * 3 + 2] = l2;
    out[OFF_JAXIS + j * 3 + 0] = x0;
    out[OFF_JAXIS + j * 3 + 1] = x1;
    out[OFF_JAXIS + j * 3 + 2] = x2;

    float aa = R00 * l0 + R01 * l1 + R02 * l2 + t0;
    float bb = R10 * l0 + R11 * l1 + R12 * l2 + t1;
    float cc = R20 * l0 + R21 * l1 + R22 * l2 + t2;
    float u = R00 * x0 + R01 * x1 + R02 * x2;
    float v = R10 * x0 + R11 * x1 + R12 * x2;
    float w = R20 * x0 + R21 * x1 + R22 * x2;
    out[OFF_NANCH + j * 3 + 0] = aa;
    out[OFF_NANCH + j * 3 + 1] = bb;
    out[OFF_NANCH + j * 3 + 2] = cc;
    out[OFF_NAXIS + j * 3 + 0] = u;
    out[OFF_NAXIS + j * 3 + 1] = v;
    out[OFF_NAXIS + j * 3 + 2] = w;

    float th = jstate[j];
    float cth = cosf(-th), sth = sinf(-th), omc = 1.f - cth;
    float rel[16];
    rel[0] = u * u + (v * v + w * w) * cth;
    rel[1] = u * v * omc - w * sth;
    rel[2] = u * w * omc + v * sth;
    rel[3] = (aa * (v * v + w * w) - u * (bb * v + cc * w)) * omc + (bb * w - cc * v) * sth;
    rel[4] = u * v * omc + w * sth;
    rel[5] = v * v + (u * u + w * w) * cth;
    rel[6] = v * w * omc - u * sth;
    rel[7] = (bb * (u * u + w * w) - v * (aa * u + cc * w)) * omc + (cc * u - aa * w) * sth;
    rel[8] = u * w * omc - v * sth;
    rel[9] = v * w * omc + u * sth;
    rel[10] = w * w + (u * u + v * v) * cth;
    rel[11] = (cc * (u * u + v * v) - w * (aa * u + bb * v)) * omc + (aa * v - bb * u) * sth;
    rel[12] = 0.f; rel[13] = 0.f; rel[14] = 0.f; rel[15] = 1.f;
    for (int i = 0; i < 16; i++) out[OFF_REL + j * 16 + i] = rel[i];

    for (int r = 0; r < 4; r++)
      for (int cix = 0; cix < 4; cix++) {
        float s = 0.f;
        for (int k2 = 0; k2 < 4; k2++) s += rel[r * 4 + k2] * T[k2 * 4 + cix];
        allT[(j + 1) * 16 + r * 4 + cix] = s;
      }
  }
}

// ---------------------------------------------------------------------------
// Kernel B (fused): norm_kp einsum + transform + weighted-distance objective.
// 2048 blocks x 256. Block covers 128 points; thread halves split the e=64
// reduction 32+32 (doubles resident waves: 8 blocks/CU = 32 waves/CU).
// Per-wave per-e access: 64 lanes x 12B contiguous (global_load_dwordx3).
// Halves combine via LDS; lower half stores norm_kp, computes distance,
// block-reduces, one atomicAdd onto out[0] (pre-set to reg term by setup).
// ---------------------------------------------------------------------------
__global__ __launch_bounds__(256) void fused_kernel(
    const float* __restrict__ W_kp, const float* __restrict__ beta,
    const float* __restrict__ pred_kp, const float* __restrict__ wgt,
    const float* __restrict__ allT, float* __restrict__ out_nkp,
    float* __restrict__ out_obj) {
  __shared__ float sb[BDIM];
  __shared__ float Ts[16];
  __shared__ float part[128 * 3];
  __shared__ float red[4];

  int tid = threadIdx.x;
  int idx = tid & 127;   // point-within-block
  int h = tid >> 7;      // e-half (wave-uniform: waves 0,1 -> h=0; 2,3 -> h=1)
  int p = blockIdx.x * 128 + idx;           // global point id
  int pid = (blockIdx.x * 128) >> 15;       // part id, block-uniform

  if (tid < BDIM) sb[tid] = beta[tid];
  if (tid < 16) Ts[tid] = allT[pid * 16 + tid];
  __syncthreads();

  const float* base = W_kp + (size_t)(h * 32) * WSTRIDE + (size_t)p * 3;
  float ax = 0.f, ay = 0.f, az = 0.f;
#pragma unroll 4
  for (int e = 0; e < 32; e++) {
    float3 vv = *(const float3*)(base + (size_t)e * WSTRIDE);
    float be = sb[h * 32 + e];
    ax = fmaf(be, vv.x, ax);
    ay = fmaf(be, vv.y, ay);
    az = fmaf(be, vv.z, az);
  }

  if (h == 1) {
    part[idx * 3 + 0] = ax;
    part[idx * 3 + 1] = ay;
    part[idx * 3 + 2] = az;
  }
  __syncthreads();

  float v = 0.f;
  if (h == 0) {
    float x = ax + part[idx * 3 + 0];
    float y = ay + part[idx * 3 + 1];
    float z = az + part[idx * 3 + 2];
    float3 o; o.x = x; o.y = y; o.z = z;
    *(float3*)(out_nkp + (size_t)p * 3) = o;

    float3 pk = *(const float3*)(pred_kp + (size_t)p * 3);
    float w = wgt[p];
    float dx = Ts[0] * x + Ts[1] * y + Ts[2]  * z + Ts[3]  - pk.x;
    float dy = Ts[4] * x + Ts[5] * y + Ts[6]  * z + Ts[7]  - pk.y;
    float dz = Ts[8] * x + Ts[9] * y + Ts[10] * z + Ts[11] - pk.z;
    v = sqrtf(dx * dx + dy * dy + dz * dz) * w;
  }
#pragma unroll
  for (int off = 32; off > 0; off >>= 1) v += __shfl_down(v, off, 64);
  if ((tid & 63) == 0) red[tid >> 6] = v;
  __syncthreads();
  if (tid == 0) {
    float s = (red[0] + red[1] + red[2] + red[3]) * (1.0f / (float)NPTS);
    atomicAdd(out_obj, s);
  }
}

extern "C" void kernel_launch(void* const* d_in, const int* in_sizes, int n_in,
                              void* d_out, int out_size, void* d_ws, size_t ws_size,
                              hipStream_t stream) {
  const float* pred_kp = (const float*)d_in[0];
  const float* quat    = (const float*)d_in[1];
  const float* base_t  = (const float*)d_in[2];
  const float* jstate  = (const float*)d_in[3];
  const float* beta    = (const float*)d_in[4];
  const float* wgt     = (const float*)d_in[5];
  const float* W_kp    = (const float*)d_in[6];
  const float* W_loc   = (const float*)d_in[7];
  const float* W_axis  = (const float*)d_in[8];
  float* out  = (float*)d_out;
  float* allT = (float*)d_ws;  // 8 * 16 floats

  setup_kernel<<<1, 64, 0, stream>>>(quat, base_t, jstate, beta, W_loc, W_axis, out, allT);
  fused_kernel<<<NPTS / 128, 256, 0, stream>>>(W_kp, beta, pred_kp, wgt, allT,
                                               out + OFF_NKPOUT, out);
}

// Round 3
// 47.056 us; speedup vs baseline: 1.2726x; 1.2453x over previous
//
#include <hip/hip_runtime.h>
#include <math.h>

#define NPARTS 8
#define NKP 32768
#define BDIM 64
#define NJ 7
#define NPTS (NPARTS * NKP)        // 262144 points
#define WSTRIDE (NPTS * 3)         // 786432 floats per beta slice
#define NBLK (NPTS / 128)          // 2048 fused blocks

// d_out flat layout (return-order concatenation)
#define OFF_OBJ    0
#define OFF_BASET  1
#define OFF_REL    17
#define OFF_NANCH  129
#define OFF_NAXIS  150
#define OFF_JLOC   171
#define OFF_JAXIS  192
#define OFF_NKPOUT 213
// total = 213 + 786432 = 786645

// d_ws layout: [0..127] allT (8 x 16 floats), [128..128+NBLK) per-block partials

// ---------------------------------------------------------------------------
// Kernel A: tiny pose math. 1 block, 64 threads. Writes small outputs and
// the 8 per-part 4x4 transforms into d_ws.
// ---------------------------------------------------------------------------
__global__ void setup_kernel(const float* __restrict__ quat,
                             const float* __restrict__ base_t,
                             const float* __restrict__ jstate,
                             const float* __restrict__ beta,
                             const float* __restrict__ W_loc,
                             const float* __restrict__ W_axis,
                             float* __restrict__ out,
                             float* __restrict__ allT) {
  int t = threadIdx.x;
  float q0 = quat[0], q1 = quat[1], q2 = quat[2], q3 = quat[3];
  float qn = sqrtf(q0 * q0 + q1 * q1 + q2 * q2 + q3 * q3);
  float a = q0 / qn, b = q1 / qn, c = q2 / qn, d = q3 / qn;
  float R00 = 1.f - 2.f * c * c - 2.f * d * d, R01 = 2.f * b * c - 2.f * a * d,
        R02 = 2.f * a * c + 2.f * b * d;
  float R10 = 2.f * b * c + 2.f * a * d, R11 = 1.f - 2.f * b * b - 2.f * d * d,
        R12 = 2.f * c * d - 2.f * a * b;
  float R20 = 2.f * b * d - 2.f * a * c, R21 = 2.f * a * b + 2.f * c * d,
        R22 = 1.f - 2.f * b * b - 2.f * c * c;
  float t0 = base_t[0], t1 = base_t[1], t2 = base_t[2];
  float T[16] = {R00, R01, R02, t0, R10, R11, R12, t1,
                 R20, R21, R22, t2, 0.f, 0.f, 0.f, 1.f};

  if (t == 7) {
    for (int i = 0; i < 16; i++) {
      out[OFF_BASET + i] = T[i];
      allT[i] = T[i];
    }
  }

  if (t < NJ) {
    int j = t;
    float l0 = 0.f, l1 = 0.f, l2 = 0.f, x0 = 0.f, x1 = 0.f, x2 = 0.f;
    for (int e = 0; e < BDIM; e++) {
      float be = beta[e];
      l0 += be * W_loc[e * 21 + j * 3 + 0];
      l1 += be * W_loc[e * 21 + j * 3 + 1];
      l2 += be * W_loc[e * 21 + j * 3 + 2];
      x0 += be * W_axis[e * 21 + j * 3 + 0];
      x1 += be * W_axis[e * 21 + j * 3 + 1];
      x2 += be * W_axis[e * 21 + j * 3 + 2];
    }
    float xn = sqrtf(x0 * x0 + x1 * x1 + x2 * x2);
    x0 /= xn; x1 /= xn; x2 /= xn;
    out[OFF_JLOC + j * 3 + 0] = l0;
    out[OFF_JLOC + j * 3 + 1] = l1;
    out[OFF_JLOC + j * 3 + 2] = l2;
    out[OFF_JAXIS + j * 3 + 0] = x0;
    out[OFF_JAXIS + j * 3 + 1] = x1;
    out[OFF_JAXIS + j * 3 + 2] = x2;

    float aa = R00 * l0 + R01 * l1 + R02 * l2 + t0;
    float bb = R10 * l0 + R11 * l1 + R12 * l2 + t1;
    float cc = R20 * l0 + R21 * l1 + R22 * l2 + t2;
    float u = R00 * x0 + R01 * x1 + R02 * x2;
    float v = R10 * x0 + R11 * x1 + R12 * x2;
    float w = R20 * x0 + R21 * x1 + R22 * x2;
    out[OFF_NANCH + j * 3 + 0] = aa;
    out[OFF_NANCH + j * 3 + 1] = bb;
    out[OFF_NANCH + j * 3 + 2] = cc;
    out[OFF_NAXIS + j * 3 + 0] = u;
    out[OFF_NAXIS + j * 3 + 1] = v;
    out[OFF_NAXIS + j * 3 + 2] = w;

    float th = jstate[j];
    float cth = cosf(-th), sth = sinf(-th), omc = 1.f - cth;
    float rel[16];
    rel[0] = u * u + (v * v + w * w) * cth;
    rel[1] = u * v * omc - w * sth;
    rel[2] = u * w * omc + v * sth;
    rel[3] = (aa * (v * v + w * w) - u * (bb * v + cc * w)) * omc + (bb * w - cc * v) * sth;
    rel[4] = u * v * omc + w * sth;
    rel[5] = v * v + (u * u + w * w) * cth;
    rel[6] = v * w * omc - u * sth;
    rel[7] = (bb * (u * u + w * w) - v * (aa * u + cc * w)) * omc + (cc * u - aa * w) * sth;
    rel[8] = u * w * omc - v * sth;
    rel[9] = v * w * omc + u * sth;
    rel[10] = w * w + (u * u + v * v) * cth;
    rel[11] = (cc * (u * u + v * v) - w * (aa * u + bb * v)) * omc + (aa * v - bb * u) * sth;
    rel[12] = 0.f; rel[13] = 0.f; rel[14] = 0.f; rel[15] = 1.f;
    for (int i = 0; i < 16; i++) out[OFF_REL + j * 16 + i] = rel[i];

    for (int r = 0; r < 4; r++)
      for (int cix = 0; cix < 4; cix++) {
        float s = 0.f;
        for (int k2 = 0; k2 < 4; k2++) s += rel[r * 4 + k2] * T[k2 * 4 + cix];
        allT[(j + 1) * 16 + r * 4 + cix] = s;
      }
  }
}

// ---------------------------------------------------------------------------
// Kernel B (fused): norm_kp einsum + transform + weighted-distance objective.
// 2048 blocks x 256; block covers 128 points; thread halves split e 32+32.
// NO same-address atomics: per-block partial sum -> d_ws (deterministic).
// ---------------------------------------------------------------------------
__global__ __launch_bounds__(256) void fused_kernel(
    const float* __restrict__ W_kp, const float* __restrict__ beta,
    const float* __restrict__ pred_kp, const float* __restrict__ wgt,
    const float* __restrict__ allT, float* __restrict__ out_nkp,
    float* __restrict__ partials) {
  __shared__ float sb[BDIM];
  __shared__ float Ts[16];
  __shared__ float part[128 * 3];
  __shared__ float red[4];

  int tid = threadIdx.x;
  int idx = tid & 127;   // point-within-block
  int h = tid >> 7;      // e-half (wave-uniform)
  int p = blockIdx.x * 128 + idx;           // global point id
  int pid = (blockIdx.x * 128) >> 15;       // part id, block-uniform

  if (tid < BDIM) sb[tid] = beta[tid];
  if (tid < 16) Ts[tid] = allT[pid * 16 + tid];
  __syncthreads();

  const float* base = W_kp + (size_t)(h * 32) * WSTRIDE + (size_t)p * 3;
  float ax = 0.f, ay = 0.f, az = 0.f;
#pragma unroll 8
  for (int e = 0; e < 32; e++) {
    float3 vv = *(const float3*)(base + (size_t)e * WSTRIDE);
    float be = sb[h * 32 + e];
    ax = fmaf(be, vv.x, ax);
    ay = fmaf(be, vv.y, ay);
    az = fmaf(be, vv.z, az);
  }

  if (h == 1) {
    part[idx * 3 + 0] = ax;
    part[idx * 3 + 1] = ay;
    part[idx * 3 + 2] = az;
  }
  __syncthreads();

  float v = 0.f;
  if (h == 0) {
    float x = ax + part[idx * 3 + 0];
    float y = ay + part[idx * 3 + 1];
    float z = az + part[idx * 3 + 2];
    float3 o; o.x = x; o.y = y; o.z = z;
    *(float3*)(out_nkp + (size_t)p * 3) = o;

    float3 pk = *(const float3*)(pred_kp + (size_t)p * 3);
    float w = wgt[p];
    float dx = Ts[0] * x + Ts[1] * y + Ts[2]  * z + Ts[3]  - pk.x;
    float dy = Ts[4] * x + Ts[5] * y + Ts[6]  * z + Ts[7]  - pk.y;
    float dz = Ts[8] * x + Ts[9] * y + Ts[10] * z + Ts[11] - pk.z;
    v = sqrtf(dx * dx + dy * dy + dz * dz) * w;
  }
#pragma unroll
  for (int off = 32; off > 0; off >>= 1) v += __shfl_down(v, off, 64);
  if ((tid & 63) == 0) red[tid >> 6] = v;
  __syncthreads();
  if (tid == 0) partials[blockIdx.x] = red[0] + red[1] + red[2] + red[3];
}

// ---------------------------------------------------------------------------
// Kernel C (finish): 1 block x 256. Deterministic reduce of 2048 partials +
// beta regularizer -> out[0]. Fixed reduction tree, same every call.
// ---------------------------------------------------------------------------
__global__ __launch_bounds__(256) void finish_kernel(
    const float* __restrict__ partials, const float* __restrict__ beta,
    float* __restrict__ out_obj) {
  __shared__ float red[4];
  int tid = threadIdx.x;
  float s = 0.f;
#pragma unroll
  for (int k = 0; k < NBLK / 256; k++) s += partials[tid + 256 * k];
#pragma unroll
  for (int off = 32; off > 0; off >>= 1) s += __shfl_down(s, off, 64);
  if ((tid & 63) == 0) red[tid >> 6] = s;
  __syncthreads();
  if (tid == 0) {
    float reg = 0.f;
    for (int e = 0; e < BDIM; e++) {
      float be = beta[e];
      reg += be * be;
    }
    float total = red[0] + red[1] + red[2] + red[3];
    out_obj[0] = total * (1.0f / (float)NPTS) + (reg / (float)BDIM) * 0.001f;
  }
}

extern "C" void kernel_launch(void* const* d_in, const int* in_sizes, int n_in,
                              void* d_out, int out_size, void* d_ws, size_t ws_size,
                              hipStream_t stream) {
  const float* pred_kp = (const float*)d_in[0];
  const float* quat    = (const float*)d_in[1];
  const float* base_t  = (const float*)d_in[2];
  const float* jstate  = (const float*)d_in[3];
  const float* beta    = (const float*)d_in[4];
  const float* wgt     = (const float*)d_in[5];
  const float* W_kp    = (const float*)d_in[6];
  const float* W_loc   = (const float*)d_in[7];
  const float* W_axis  = (const float*)d_in[8];
  float* out      = (float*)d_out;
  float* allT     = (float*)d_ws;            // 128 floats
  float* partials = (float*)d_ws + 128;      // NBLK floats

  setup_kernel<<<1, 64, 0, stream>>>(quat, base_t, jstate, beta, W_loc, W_axis, out, allT);
  fused_kernel<<<NBLK, 256, 0, stream>>>(W_kp, beta, pred_kp, wgt, allT,
                                         out + OFF_NKPOUT, partials);
  finish_kernel<<<1, 256, 0, stream>>>(partials, beta, out);
}